// Round 1
// baseline (227.800 us; speedup 1.0000x reference)
//
#include <hip/hip_runtime.h>
#include <math.h>

#define NCLS 81
#define A_ANCH 8732
#define B_BATCH 64
#define EPSF 1e-7f

// ---------------- workspace layout ----------------
// [0]                      neg_ce  : B*A floats (8,941,568 B)
// [NEG_BYTES]              pos_loss: B floats
// [+256]                   loc_loss: B floats
// [+512]                   nm      : B ints
// [+768] (8-aligned)       accum   : 2 doubles (conf_sum, loc_sum)
// [+784]                   hits    : 1 unsigned long long
static const size_t NEG_BYTES = (size_t)B_BATCH * A_ANCH * sizeof(float);

__device__ __forceinline__ float wave_reduce_max(float v) {
    for (int off = 32; off; off >>= 1) v = fmaxf(v, __shfl_xor(v, off));
    return v;
}
__device__ __forceinline__ float wave_reduce_sum(float v) {
    for (int off = 32; off; off >>= 1) v += __shfl_xor(v, off);
    return v;
}

__device__ __forceinline__ int block_reduce_i(int v, int* sred) {
    for (int off = 32; off; off >>= 1) v += __shfl_xor(v, off);
    int wid = threadIdx.x >> 6, lane = threadIdx.x & 63;
    if (lane == 0) sred[wid] = v;
    __syncthreads();
    int r = sred[0] + sred[1] + sred[2] + sred[3];
    __syncthreads();
    return r;
}
__device__ __forceinline__ float block_reduce_f(float v, float* sred) {
    for (int off = 32; off; off >>= 1) v += __shfl_xor(v, off);
    int wid = threadIdx.x >> 6, lane = threadIdx.x & 63;
    if (lane == 0) sred[wid] = v;
    __syncthreads();
    float r = sred[0] + sred[1] + sred[2] + sred[3];
    __syncthreads();
    return r;
}

// ---------------- K0: zero accumulators ----------------
__global__ void zero_kernel(float* pos_loss, float* loc_loss, int* nm,
                            double* accum, unsigned long long* hits) {
    int t = threadIdx.x;
    if (t < B_BATCH) { pos_loss[t] = 0.f; loc_loss[t] = 0.f; nm[t] = 0; }
    if (t == 64) { accum[0] = 0.0; accum[1] = 0.0; *hits = 0ull; }
}

// ---------------- K1: per-anchor logsumexp + CE + GIoU ----------------
// grid: B * ceil(A/32) blocks of 256 threads (4 waves), each wave handles 8 anchors.
#define BLOCKS_PER_BATCH ((A_ANCH + 31) / 32)   // 273

__global__ __launch_bounds__(256) void anchor_kernel(
    const float* __restrict__ conf, const float* __restrict__ loc,
    const float* __restrict__ tgt, float* __restrict__ neg_ce,
    float* __restrict__ pos_loss, float* __restrict__ loc_loss, int* __restrict__ nm)
{
    int b   = blockIdx.x / BLOCKS_PER_BATCH;
    int blk = blockIdx.x % BLOCKS_PER_BATCH;
    int wave = threadIdx.x >> 6;
    int lane = threadIdx.x & 63;

    float lpos = 0.f, lloc = 0.f;
    int lnm = 0;

    for (int i = 0; i < 8; ++i) {
        int a = blk * 32 + i * 4 + wave;   // 4 consecutive anchors across the 4 waves
        if (a >= A_ANCH) break;
        size_t ridx = (size_t)b * A_ANCH + a;
        size_t row  = ridx * NCLS;

        float x0 = conf[row + lane];
        float x1 = (lane < NCLS - 64) ? conf[row + 64 + lane] : -INFINITY;

        float m = wave_reduce_max(fmaxf(x0, x1));
        float e = expf(x0 - m) + ((lane < NCLS - 64) ? expf(x1 - m) : 0.f);
        float s = wave_reduce_sum(e);

        if (lane == 0) {
            float lse = m + logf(s);
            int label = (int)tgt[ridx * 5 + 4];
            if (label > 0) {
                lpos += lse - conf[row + label];
                lnm  += 1;
                const float* p = loc + ridx * 4;
                const float* t = tgt + ridx * 5;
                float px1 = p[0], py1 = p[1], px2 = p[2], py2 = p[3];
                float tx1 = t[0], ty1 = t[1], tx2 = t[2], ty2 = t[3];
                float area_p = (px2 - px1) * (py2 - py1);
                float area_t = (tx2 - tx1) * (ty2 - ty1);
                float iw = fmaxf(fminf(px2, tx2) - fmaxf(px1, tx1), 0.f);
                float ih = fmaxf(fminf(py2, ty2) - fmaxf(py1, ty1), 0.f);
                float inter = iw * ih;
                float uni   = area_p + area_t - inter;
                float iou   = inter / (uni + EPSF);
                float cw = fmaxf(px2, tx2) - fminf(px1, tx1);
                float ch = fmaxf(py2, ty2) - fminf(py1, ty1);
                float area_c = cw * ch;
                float giou = iou - (area_c - uni) / (area_c + EPSF);
                lloc += 1.f - giou;
                neg_ce[ridx] = -1.f;
            } else {
                neg_ce[ridx] = lse - x0;   // lane 0's x0 == conf[row + 0]
            }
        }
    }

    __shared__ float sp[4], sl[4];
    __shared__ int   sn[4];
    if (lane == 0) { sp[wave] = lpos; sl[wave] = lloc; sn[wave] = lnm; }
    __syncthreads();
    if (threadIdx.x == 0) {
        atomicAdd(&pos_loss[b], sp[0] + sp[1] + sp[2] + sp[3]);
        atomicAdd(&loc_loss[b], sl[0] + sl[1] + sl[2] + sl[3]);
        atomicAdd(&nm[b],       sn[0] + sn[1] + sn[2] + sn[3]);
    }
}

// ---------------- K2: per-batch top-k sum (hard negative mining) ----------------
__global__ __launch_bounds__(256) void topk_kernel(
    const float* __restrict__ neg_ce, const float* __restrict__ pos_loss,
    const float* __restrict__ loc_loss, const int* __restrict__ nm,
    double* __restrict__ accum, unsigned long long* __restrict__ hits)
{
    __shared__ float sv[A_ANCH];
    __shared__ float fred[4];
    __shared__ int   ired[4];
    int b = blockIdx.x;
    int tid = threadIdx.x;

    for (int i = tid; i < A_ANCH; i += 256) sv[i] = neg_ce[(size_t)b * A_ANCH + i];
    __syncthreads();

    int k = 3 * nm[b];

    // count & sum of all non-negative entries (pos anchors are -1)
    int c0 = 0; float sall = 0.f;
    for (int i = tid; i < A_ANCH; i += 256) {
        float v = sv[i];
        if (v >= 0.f) { c0++; sall += v; }
    }
    c0   = block_reduce_i(c0, ired);
    sall = block_reduce_f(sall, fred);

    float negl = 0.f;
    if (k > 0) {
        if (k >= c0) {
            negl = sall;            // take everything non-negative
        } else {
            // binary search on IEEE bits for the k-th largest value.
            // invariant: count(v >= as_float(lo)) >= k, count(v >= as_float(hi)) < k
            unsigned lo = 0u, hi = 0x7F800000u;
            while (hi - lo > 1u) {
                unsigned mid = lo + (hi - lo) / 2u;
                float thr = __uint_as_float(mid);   // > 0, so excludes the -1 markers
                int c = 0;
                for (int i = tid; i < A_ANCH; i += 256) {
                    if (sv[i] >= thr) c++;
                }
                c = block_reduce_i(c, ired);
                if (c >= k) lo = mid; else hi = mid;
            }
            float t = __uint_as_float(lo);          // k-th largest value
            int cg = 0; float sg = 0.f;
            for (int i = tid; i < A_ANCH; i += 256) {
                float v = sv[i];
                if (v > t) { cg++; sg += v; }
            }
            cg = block_reduce_i(cg, ired);
            sg = block_reduce_f(sg, fred);
            negl = sg + (float)(k - cg) * t;        // ties contribute value t
        }
    }

    if (tid == 0) {
        atomicAdd(&accum[0], (double)(pos_loss[b] + negl));
        atomicAdd(&accum[1], (double)loc_loss[b]);
        atomicAdd(hits, (unsigned long long)nm[b]);
    }
}

// ---------------- K3: finalize ----------------
__global__ void finalize_kernel(const double* __restrict__ accum,
                                const unsigned long long* __restrict__ hits,
                                float* __restrict__ out) {
    if (threadIdx.x == 0 && blockIdx.x == 0) {
        double conf_s = accum[0], loc_s = accum[1];
        unsigned long long h = *hits;
        double denom = (double)(h > 0 ? h : 1ull);
        if (h > 0) {
            out[0] = (float)((conf_s + loc_s) / denom);
            out[1] = (float)(conf_s / denom);
            out[2] = (float)(loc_s / denom);
        } else {
            out[0] = 0.f; out[1] = 0.f; out[2] = 0.f;
        }
    }
}

extern "C" void kernel_launch(void* const* d_in, const int* in_sizes, int n_in,
                              void* d_out, int out_size, void* d_ws, size_t ws_size,
                              hipStream_t stream) {
    const float* conf = (const float*)d_in[0];
    const float* loc  = (const float*)d_in[1];
    const float* tgt  = (const float*)d_in[2];
    float* out = (float*)d_out;

    char* ws = (char*)d_ws;
    float* neg_ce   = (float*)ws;
    float* pos_loss = (float*)(ws + NEG_BYTES);
    float* loc_loss = (float*)(ws + NEG_BYTES + 256);
    int*   nm       = (int*)  (ws + NEG_BYTES + 512);
    double* accum   = (double*)(ws + NEG_BYTES + 768);
    unsigned long long* hits = (unsigned long long*)(ws + NEG_BYTES + 784);

    zero_kernel<<<1, 128, 0, stream>>>(pos_loss, loc_loss, nm, accum, hits);
    anchor_kernel<<<dim3(B_BATCH * BLOCKS_PER_BATCH), dim3(256), 0, stream>>>(
        conf, loc, tgt, neg_ce, pos_loss, loc_loss, nm);
    topk_kernel<<<dim3(B_BATCH), dim3(256), 0, stream>>>(
        neg_ce, pos_loss, loc_loss, nm, accum, hits);
    finalize_kernel<<<1, 64, 0, stream>>>(accum, hits, out);
}

// Round 2
// 84.478 us; speedup vs baseline: 2.6965x; 2.6965x over previous
//
#include <hip/hip_runtime.h>
#include <math.h>

#define NCLS 81
#define A_ANCH 8732
#define B_BATCH 64
#define EPSF 1e-7f
#define TA 128
#define NB ((A_ANCH + TA - 1) / TA)   // 69 blocks per batch (68 full + tail of 28)

// ---------------- workspace layout ----------------
// [0]          neg_ce  : B*A floats
// [NEG_BYTES]  pos_loss: B floats
// [+256]       loc_loss: B floats
// [+512]       nm      : B ints
// [+768]       accum   : 2 doubles
// [+784]       hits    : 1 ull
static const size_t NEG_BYTES = (size_t)B_BATCH * A_ANCH * sizeof(float);

#define GLOAD_LDS16(g, l) __builtin_amdgcn_global_load_lds( \
    (const __attribute__((address_space(1))) void*)(g),      \
    (__attribute__((address_space(3))) void*)(l), 16, 0, 0)
#define GLOAD_LDS4(g, l) __builtin_amdgcn_global_load_lds(  \
    (const __attribute__((address_space(1))) void*)(g),      \
    (__attribute__((address_space(3))) void*)(l), 4, 0, 0)

// ---------------- K0: zero accumulators ----------------
__global__ void zero_kernel(float* pos_loss, float* loc_loss, int* nm,
                            double* accum, unsigned long long* hits) {
    int t = threadIdx.x;
    if (t < B_BATCH) { pos_loss[t] = 0.f; loc_loss[t] = 0.f; nm[t] = 0; }
    if (t == 64) { accum[0] = 0.0; accum[1] = 0.0; *hits = 0ull; }
}

// ---------------- K1: per-anchor logsumexp + CE + GIoU ----------------
// One thread per anchor. Tile of 128 anchor rows staged in LDS.
__global__ __launch_bounds__(TA) void anchor_kernel(
    const float* __restrict__ conf, const float* __restrict__ loc,
    const float* __restrict__ tgt, float* __restrict__ neg_ce,
    float* __restrict__ pos_loss, float* __restrict__ loc_loss, int* __restrict__ nm)
{
    __shared__ float sconf[TA * NCLS];   // 41,472 B
    __shared__ float s_pos, s_loc;
    __shared__ int   s_nm;

    int b   = blockIdx.x / NB;
    int blk = blockIdx.x % NB;
    int tid = threadIdx.x;
    int wv  = tid >> 6, ln = tid & 63;
    int rows = A_ANCH - blk * TA; if (rows > TA) rows = TA;
    const float* gsrc = conf + ((size_t)b * A_ANCH + (size_t)blk * TA) * NCLS;

    if (rows == TA) {
        // 128*81 floats = 40 chunks of 1024B (width-16) + one 512B chunk (width-4)
        #pragma unroll 4
        for (int c = wv; c < 40; c += 2) {
            GLOAD_LDS16(gsrc + c * 256 + ln * 4, sconf + c * 256);
        }
        GLOAD_LDS4(gsrc + 10240 + wv * 64 + ln, sconf + 10240 + wv * 64);
    } else {
        int n = rows * NCLS;
        for (int i = tid; i < n; i += TA) sconf[i] = gsrc[i];
    }
    if (tid == 0) { s_pos = 0.f; s_loc = 0.f; s_nm = 0; }
    __syncthreads();   // compiler drains vmcnt before s_barrier

    if (tid < rows) {
        const float* r = sconf + tid * NCLS;   // stride 81: 2-way bank alias = free
        float s0 = 0.f, s1 = 0.f, s2 = 0.f, s3 = 0.f;
        #pragma unroll
        for (int j = 0; j < 80; j += 4) {
            s0 += __expf(r[j]);
            s1 += __expf(r[j + 1]);
            s2 += __expf(r[j + 2]);
            s3 += __expf(r[j + 3]);
        }
        float s   = (s0 + s1) + (s2 + s3) + __expf(r[80]);
        float lse = __logf(s);

        size_t ridx = (size_t)b * A_ANCH + (size_t)blk * TA + tid;
        int label = (int)tgt[ridx * 5 + 4];
        if (label > 0) {
            float ce = lse - r[label];
            const float* p = loc + ridx * 4;
            float px1 = p[0], py1 = p[1], px2 = p[2], py2 = p[3];
            const float* t = tgt + ridx * 5;
            float tx1 = t[0], ty1 = t[1], tx2 = t[2], ty2 = t[3];
            float area_p = (px2 - px1) * (py2 - py1);
            float area_t = (tx2 - tx1) * (ty2 - ty1);
            float iw = fmaxf(fminf(px2, tx2) - fmaxf(px1, tx1), 0.f);
            float ih = fmaxf(fminf(py2, ty2) - fmaxf(py1, ty1), 0.f);
            float inter = iw * ih;
            float uni   = area_p + area_t - inter;
            float iou   = inter / (uni + EPSF);
            float cw = fmaxf(px2, tx2) - fminf(px1, tx1);
            float ch = fmaxf(py2, ty2) - fminf(py1, ty1);
            float area_c = cw * ch;
            float giou = iou - (area_c - uni) / (area_c + EPSF);
            atomicAdd(&s_pos, ce);
            atomicAdd(&s_loc, 1.f - giou);
            atomicAdd(&s_nm, 1);
            neg_ce[ridx] = -1.f;
        } else {
            neg_ce[ridx] = fmaxf(lse - r[0], 0.f);
        }
    }
    __syncthreads();
    if (tid == 0) {
        atomicAdd(&pos_loss[b], s_pos);
        atomicAdd(&loc_loss[b], s_loc);
        atomicAdd(&nm[b],       s_nm);
    }
}

// ---------------- K2: per-batch top-k sum (hard negative mining) ----------------
#define K2_T 1024
#define VPT 9   // ceil(8732/1024)

__global__ __launch_bounds__(K2_T) void topk_kernel(
    const float* __restrict__ neg_ce, const float* __restrict__ pos_loss,
    const float* __restrict__ loc_loss, const int* __restrict__ nm,
    double* __restrict__ accum, unsigned long long* __restrict__ hits)
{
    __shared__ int   cnt[36];   // one pre-zeroed slot per binary-search iteration
    __shared__ float fsum[4];
    int b = blockIdx.x, tid = threadIdx.x;
    int lane = tid & 63;
    if (tid < 36) cnt[tid] = 0;
    if (tid < 4)  fsum[tid] = 0.f;

    float v[VPT];
    #pragma unroll
    for (int i = 0; i < VPT; ++i) {
        int idx = tid + i * K2_T;
        v[i] = (idx < A_ANCH) ? neg_ce[(size_t)b * A_ANCH + idx] : -1.f;
    }

    // count & sum of all non-negative entries
    int c = 0; float s = 0.f;
    #pragma unroll
    for (int i = 0; i < VPT; ++i) { if (v[i] >= 0.f) { c++; s += v[i]; } }
    for (int off = 32; off; off >>= 1) { c += __shfl_xor(c, off); s += __shfl_xor(s, off); }
    __syncthreads();
    if (lane == 0) { atomicAdd(&cnt[32], c); atomicAdd(&fsum[0], s); }
    __syncthreads();
    int c0 = cnt[32]; float sall = fsum[0];
    int k = 3 * nm[b];

    float negl = 0.f;
    if (k >= c0) {
        negl = sall;
    } else if (k > 0) {
        // binary search on IEEE bits for the k-th largest value (values >= 0)
        unsigned lo = 0u, hi = 0x7F800000u;
        int it = 0;
        while (hi - lo > 1u) {            // exactly 31 uniform iterations
            unsigned mid = lo + (hi - lo) / 2u;
            float thr = __uint_as_float(mid);   // > 0: excludes the -1 pos markers
            int cc = 0;
            #pragma unroll
            for (int i = 0; i < VPT; ++i) cc += (v[i] >= thr) ? 1 : 0;
            for (int off = 32; off; off >>= 1) cc += __shfl_xor(cc, off);
            if (lane == 0) atomicAdd(&cnt[it], cc);
            __syncthreads();
            if (cnt[it] >= k) lo = mid; else hi = mid;
            ++it;
        }
        float t = __uint_as_float(lo);    // k-th largest value
        int cg = 0; float sg = 0.f;
        #pragma unroll
        for (int i = 0; i < VPT; ++i) { if (v[i] > t) { cg++; sg += v[i]; } }
        for (int off = 32; off; off >>= 1) { cg += __shfl_xor(cg, off); sg += __shfl_xor(sg, off); }
        if (lane == 0) { atomicAdd(&cnt[33], cg); atomicAdd(&fsum[1], sg); }
        __syncthreads();
        negl = fsum[1] + (float)(k - cnt[33]) * t;   // ties contribute value t
    }

    if (tid == 0) {
        atomicAdd(&accum[0], (double)(pos_loss[b] + negl));
        atomicAdd(&accum[1], (double)loc_loss[b]);
        atomicAdd(hits, (unsigned long long)nm[b]);
    }
}

// ---------------- K3: finalize ----------------
__global__ void finalize_kernel(const double* __restrict__ accum,
                                const unsigned long long* __restrict__ hits,
                                float* __restrict__ out) {
    if (threadIdx.x == 0 && blockIdx.x == 0) {
        double conf_s = accum[0], loc_s = accum[1];
        unsigned long long h = *hits;
        double denom = (double)(h > 0 ? h : 1ull);
        if (h > 0) {
            out[0] = (float)((conf_s + loc_s) / denom);
            out[1] = (float)(conf_s / denom);
            out[2] = (float)(loc_s / denom);
        } else {
            out[0] = 0.f; out[1] = 0.f; out[2] = 0.f;
        }
    }
}

extern "C" void kernel_launch(void* const* d_in, const int* in_sizes, int n_in,
                              void* d_out, int out_size, void* d_ws, size_t ws_size,
                              hipStream_t stream) {
    const float* conf = (const float*)d_in[0];
    const float* loc  = (const float*)d_in[1];
    const float* tgt  = (const float*)d_in[2];
    float* out = (float*)d_out;

    char* ws = (char*)d_ws;
    float* neg_ce   = (float*)ws;
    float* pos_loss = (float*)(ws + NEG_BYTES);
    float* loc_loss = (float*)(ws + NEG_BYTES + 256);
    int*   nm       = (int*)  (ws + NEG_BYTES + 512);
    double* accum   = (double*)(ws + NEG_BYTES + 768);
    unsigned long long* hits = (unsigned long long*)(ws + NEG_BYTES + 784);

    zero_kernel<<<1, 128, 0, stream>>>(pos_loss, loc_loss, nm, accum, hits);
    anchor_kernel<<<dim3(B_BATCH * NB), dim3(TA), 0, stream>>>(
        conf, loc, tgt, neg_ce, pos_loss, loc_loss, nm);
    topk_kernel<<<dim3(B_BATCH), dim3(K2_T), 0, stream>>>(
        neg_ce, pos_loss, loc_loss, nm, accum, hits);
    finalize_kernel<<<1, 64, 0, stream>>>(accum, hits, out);
}